// Round 4
// baseline (247.383 us; speedup 1.0000x reference)
//
#include <hip/hip_runtime.h>

// GCN1 on MI355X. Round-3 evidence: consumer kernels (k_accB3 92.9us) were
// latency-bound — 245 blocks (1/CU, 41% occ), serial per-edge chain
// load->gather->LDS-atomic, 8% HBM. Round-4: 4x ILP unroll + S-way bucket
// sub-split into partial arrays (grid ~1960) + separate node epilogues +
// nontemporal streaming of packed.
//
// Algebra (validated, absmax 3.9e-3): layer1 collapses to scalar aggregate
// (x is [N,1]); layer2 aggregates only the 2-wide y = h1@W2.

static constexpr int BKT_BITS = 11;
static constexpr int BKT = 1 << BKT_BITS;  // 2048 nodes/bucket
static constexpr int NB = 256;             // padded bucket count (nbkt=245)
static constexpr int HB = 512;             // hist blocks
static constexpr int HT = 256;
static constexpr int CHUNK = 8192;         // edges per scatter block
static constexpr int SCT = 256;
static constexpr int PERT = CHUNK / SCT;   // 32 edges/thread
static constexpr int AT = 256;             // threads in part kernels

// ---- 1. per-bucket totals: LDS histogram, one global add per bucket ----
__global__ void __launch_bounds__(HT) k_hist(const int* __restrict__ dst, int e,
                                             int chunk, int nbkt,
                                             unsigned* __restrict__ totals) {
  __shared__ unsigned cnt[NB];
  for (int t = threadIdx.x; t < NB; t += HT) cnt[t] = 0;
  __syncthreads();
  int lo = blockIdx.x * chunk;  // chunk multiple of 4
  int hi = min(lo + chunk, e);
  const int4* d4 = (const int4*)dst;
  for (int i = (lo >> 2) + threadIdx.x; i < (hi >> 2); i += HT) {
    int4 d = d4[i];
    atomicAdd(&cnt[((unsigned)d.x) >> BKT_BITS], 1u);
    atomicAdd(&cnt[((unsigned)d.y) >> BKT_BITS], 1u);
    atomicAdd(&cnt[((unsigned)d.z) >> BKT_BITS], 1u);
    atomicAdd(&cnt[((unsigned)d.w) >> BKT_BITS], 1u);
  }
  for (int i = ((hi >> 2) << 2) + threadIdx.x; i < hi; i += HT)
    atomicAdd(&cnt[((unsigned)dst[i]) >> BKT_BITS], 1u);
  __syncthreads();
  for (int t = threadIdx.x; t < nbkt; t += HT)
    if (cnt[t]) atomicAdd(&totals[t], cnt[t]);
}

// ---- 2. exclusive scan of totals -> gcur (single wave) ----
__global__ void k_basescan(const unsigned* __restrict__ totals, int nbkt,
                           unsigned* __restrict__ gcur) {
  int lane = threadIdx.x;  // blockDim = 64
  unsigned running = 0;
  for (int c = 0; c < NB; c += 64) {
    int k = c + lane;
    unsigned v = (k < nbkt) ? totals[k] : 0u;
    unsigned incl = v;
#pragma unroll
    for (int off = 1; off < 64; off <<= 1) {
      unsigned t = __shfl_up(incl, off);
      if (lane >= off) incl += t;
    }
    if (k < nbkt) gcur[k] = running + incl - v;
    running += __shfl(incl, 63);
  }
}

// ---- 3. scatter: block-local counting sort + linear copy-out ----
__global__ void __launch_bounds__(SCT) k_scatter(
    const int* __restrict__ src, const int* __restrict__ dst, int e, int nbkt,
    unsigned* __restrict__ gcur, unsigned* __restrict__ packed) {
  __shared__ unsigned staged[CHUNK];  // 32 KB
  __shared__ unsigned cnt[NB];
  __shared__ unsigned cur[NB];
  __shared__ unsigned gseg[NB];
  __shared__ unsigned loff[NB + 1];
  const int tid = threadIdx.x;
  const int lo = blockIdx.x * CHUNK;
  for (int t = tid; t < NB; t += SCT) { cnt[t] = 0u; cur[t] = 0u; }
  __syncthreads();

  unsigned pk[PERT];
  unsigned bku[PERT / 4];
  const int4* s4 = (const int4*)src;
  const int4* d4 = (const int4*)dst;
#pragma unroll
  for (int jj = 0; jj < PERT / 4; ++jj) {
    int i4 = (lo >> 2) + jj * SCT + tid;
    unsigned b4 = 0xFFFFFFFFu;
    if (i4 * 4 + 3 < e) {
      int4 s = s4[i4];
      int4 d = d4[i4];
      unsigned k0 = ((unsigned)d.x) >> BKT_BITS, k1 = ((unsigned)d.y) >> BKT_BITS;
      unsigned k2 = ((unsigned)d.z) >> BKT_BITS, k3 = ((unsigned)d.w) >> BKT_BITS;
      pk[jj * 4 + 0] = ((unsigned)s.x << BKT_BITS) | ((unsigned)d.x & (BKT - 1));
      pk[jj * 4 + 1] = ((unsigned)s.y << BKT_BITS) | ((unsigned)d.y & (BKT - 1));
      pk[jj * 4 + 2] = ((unsigned)s.z << BKT_BITS) | ((unsigned)d.z & (BKT - 1));
      pk[jj * 4 + 3] = ((unsigned)s.w << BKT_BITS) | ((unsigned)d.w & (BKT - 1));
      b4 = k0 | (k1 << 8) | (k2 << 16) | (k3 << 24);
      atomicAdd(&cnt[k0], 1u);
      atomicAdd(&cnt[k1], 1u);
      atomicAdd(&cnt[k2], 1u);
      atomicAdd(&cnt[k3], 1u);
    } else {
#pragma unroll
      for (int c = 0; c < 4; ++c) {
        int i = i4 * 4 + c;
        if (i >= lo && i < e) {
          unsigned dd = (unsigned)dst[i];
          unsigned kk = dd >> BKT_BITS;
          pk[jj * 4 + c] = ((unsigned)src[i] << BKT_BITS) | (dd & (BKT - 1));
          b4 = (b4 & ~(0xFFu << (8 * c))) | (kk << (8 * c));
          atomicAdd(&cnt[kk], 1u);
        }
      }
    }
    bku[jj] = b4;
  }
  __syncthreads();

  if (tid < 64) {  // scan cnt -> loff
    unsigned running = 0;
    for (int c = 0; c < NB; c += 64) {
      int k = c + tid;
      unsigned v = cnt[k];
      unsigned incl = v;
#pragma unroll
      for (int off = 1; off < 64; off <<= 1) {
        unsigned t = __shfl_up(incl, off);
        if (tid >= off) incl += t;
      }
      loff[k] = running + incl - v;
      running += __shfl(incl, 63);
    }
    if (tid == 0) loff[NB] = running;
  }
  __syncthreads();

  for (int k = tid; k < nbkt; k += SCT)
    if (cnt[k]) gseg[k] = atomicAdd(&gcur[k], cnt[k]);

#pragma unroll
  for (int jj = 0; jj < PERT / 4; ++jj) {
    unsigned b4 = bku[jj];
#pragma unroll
    for (int c = 0; c < 4; ++c) {
      unsigned k = (b4 >> (8 * c)) & 0xFFu;
      if (k != 0xFFu) {
        unsigned pos = loff[k] + atomicAdd(&cur[k], 1u);
        staged[pos] = pk[jj * 4 + c];
      }
    }
  }
  __syncthreads();

  int mv = (int)loff[nbkt];
  for (int t = tid; t < mv; t += SCT) {
    int a = 0, b = nbkt;
    while (b - a > 1) {
      int mid = (a + b) >> 1;
      if ((int)loff[mid] <= t) a = mid; else b = mid;
    }
    __builtin_nontemporal_store(staged[t],
                                packed + gseg[a] + (unsigned)(t - (int)loff[a]));
  }
}

// ---- 4. per-bucket degree -> dinv, xs = dinv*x (4x unrolled) ----
__global__ void __launch_bounds__(1024) k_degnode(
    const unsigned* __restrict__ packed, const unsigned* __restrict__ gcur,
    const float* __restrict__ x, int n, float* __restrict__ dinv,
    float* __restrict__ xs) {
  __shared__ unsigned cnt[BKT];
  int k = blockIdx.x;
  for (int t = threadIdx.x; t < BKT; t += 1024) cnt[t] = 0;
  __syncthreads();
  unsigned lo = k ? gcur[k - 1] : 0u, hi = gcur[k];
  unsigned i = lo + threadIdx.x;
  for (; i + 3u * 1024u < hi; i += 4096u) {
    unsigned p0 = __builtin_nontemporal_load(packed + i);
    unsigned p1 = __builtin_nontemporal_load(packed + i + 1024);
    unsigned p2 = __builtin_nontemporal_load(packed + i + 2048);
    unsigned p3 = __builtin_nontemporal_load(packed + i + 3072);
    atomicAdd(&cnt[p0 & (BKT - 1)], 1u);
    atomicAdd(&cnt[p1 & (BKT - 1)], 1u);
    atomicAdd(&cnt[p2 & (BKT - 1)], 1u);
    atomicAdd(&cnt[p3 & (BKT - 1)], 1u);
  }
  for (; i < hi; i += 1024u) atomicAdd(&cnt[packed[i] & (BKT - 1)], 1u);
  __syncthreads();
  int g0 = k << BKT_BITS;
  for (int t = threadIdx.x; t < BKT; t += 1024) {
    int g = g0 + t;
    if (g < n) {
      float di = rsqrtf((float)(cnt[t] + 1u));  // +1 self-loop
      dinv[g] = di;
      xs[g] = di * x[g];
    }
  }
}

// ---- 5a. layer-1 partial aggregate (S-way split, 4x unroll) ----
__global__ void __launch_bounds__(AT) k_accA_part(
    const unsigned* __restrict__ packed, const unsigned* __restrict__ gcur,
    const float* __restrict__ xs, int S, float* __restrict__ pA) {
  __shared__ float acc[BKT];
  int k = blockIdx.x / S, s = blockIdx.x - k * S;
  for (int t = threadIdx.x; t < BKT; t += AT) acc[t] = 0.0f;
  __syncthreads();
  unsigned blo = k ? gcur[k - 1] : 0u, bhi = gcur[k];
  unsigned slice = (bhi - blo + S - 1) / S;
  unsigned lo = blo + s * slice;
  unsigned hi = lo + slice;
  if (hi > bhi) hi = bhi;
  if (lo > bhi) lo = bhi;
  unsigned i = lo + threadIdx.x;
  for (; i + 3u * AT < hi; i += 4u * AT) {
    unsigned p0 = __builtin_nontemporal_load(packed + i);
    unsigned p1 = __builtin_nontemporal_load(packed + i + AT);
    unsigned p2 = __builtin_nontemporal_load(packed + i + 2 * AT);
    unsigned p3 = __builtin_nontemporal_load(packed + i + 3 * AT);
    float v0 = xs[p0 >> BKT_BITS];
    float v1 = xs[p1 >> BKT_BITS];
    float v2 = xs[p2 >> BKT_BITS];
    float v3 = xs[p3 >> BKT_BITS];
    atomicAdd(&acc[p0 & (BKT - 1)], v0);
    atomicAdd(&acc[p1 & (BKT - 1)], v1);
    atomicAdd(&acc[p2 & (BKT - 1)], v2);
    atomicAdd(&acc[p3 & (BKT - 1)], v3);
  }
  for (; i < hi; i += AT) {
    unsigned p = packed[i];
    atomicAdd(&acc[p & (BKT - 1)], xs[p >> BKT_BITS]);
  }
  __syncthreads();
  float* dstp = pA + ((size_t)(k * S + s) << BKT_BITS);
  for (int t = threadIdx.x; t < BKT; t += AT)
    __builtin_nontemporal_store(acc[t], dstp + t);
}

// ---- 5b. node epilogue A: sum partials + fused MLP 1->32->2 -> yd ----
__global__ void __launch_bounds__(256) k_nodeA(
    const float* __restrict__ pA, const float* __restrict__ dinv,
    const float* __restrict__ xs, const float* __restrict__ W1,
    const float* __restrict__ b1, const float* __restrict__ W2, int S, int n,
    float2* __restrict__ yd) {
  __shared__ float sW1[32], sb1[32], sW2[64];
  if (threadIdx.x < 32) {
    sW1[threadIdx.x] = W1[threadIdx.x];
    sb1[threadIdx.x] = b1[threadIdx.x];
  } else if (threadIdx.x < 96) {
    sW2[threadIdx.x - 32] = W2[threadIdx.x - 32];
  }
  __syncthreads();
  int g = blockIdx.x * 256 + threadIdx.x;
  if (g >= n) return;
  int k = g >> BKT_BITS, t = g & (BKT - 1);
  float a = 0.0f;
  for (int s = 0; s < S; ++s) a += pA[((size_t)(k * S + s) << BKT_BITS) + t];
  float di = dinv[g];
  float sv = di * (a + xs[g]);  // self-loop: dinv^2*x = dinv*xs
  float y0 = 0.0f, y1 = 0.0f;
#pragma unroll
  for (int f = 0; f < 32; ++f) {
    float h = fmaxf(fmaf(sv, sW1[f], sb1[f]), 0.0f);
    y0 = fmaf(h, sW2[2 * f + 0], y0);
    y1 = fmaf(h, sW2[2 * f + 1], y1);
  }
  yd[g] = make_float2(di * y0, di * y1);
}

// ---- 6a. layer-2 partial aggregate (float2) ----
__global__ void __launch_bounds__(AT) k_accB_part(
    const unsigned* __restrict__ packed, const unsigned* __restrict__ gcur,
    const float2* __restrict__ yd, int S, float2* __restrict__ pB) {
  __shared__ float2 av[BKT];  // 16 KB
  int k = blockIdx.x / S, s = blockIdx.x - k * S;
  for (int t = threadIdx.x; t < BKT; t += AT) av[t] = make_float2(0.0f, 0.0f);
  __syncthreads();
  unsigned blo = k ? gcur[k - 1] : 0u, bhi = gcur[k];
  unsigned slice = (bhi - blo + S - 1) / S;
  unsigned lo = blo + s * slice;
  unsigned hi = lo + slice;
  if (hi > bhi) hi = bhi;
  if (lo > bhi) lo = bhi;
  unsigned i = lo + threadIdx.x;
  for (; i + 3u * AT < hi; i += 4u * AT) {
    unsigned p0 = __builtin_nontemporal_load(packed + i);
    unsigned p1 = __builtin_nontemporal_load(packed + i + AT);
    unsigned p2 = __builtin_nontemporal_load(packed + i + 2 * AT);
    unsigned p3 = __builtin_nontemporal_load(packed + i + 3 * AT);
    float2 v0 = yd[p0 >> BKT_BITS];
    float2 v1 = yd[p1 >> BKT_BITS];
    float2 v2 = yd[p2 >> BKT_BITS];
    float2 v3 = yd[p3 >> BKT_BITS];
    atomicAdd(&av[p0 & (BKT - 1)].x, v0.x);
    atomicAdd(&av[p0 & (BKT - 1)].y, v0.y);
    atomicAdd(&av[p1 & (BKT - 1)].x, v1.x);
    atomicAdd(&av[p1 & (BKT - 1)].y, v1.y);
    atomicAdd(&av[p2 & (BKT - 1)].x, v2.x);
    atomicAdd(&av[p2 & (BKT - 1)].y, v2.y);
    atomicAdd(&av[p3 & (BKT - 1)].x, v3.x);
    atomicAdd(&av[p3 & (BKT - 1)].y, v3.y);
  }
  for (; i < hi; i += AT) {
    unsigned p = packed[i];
    float2 v = yd[p >> BKT_BITS];
    atomicAdd(&av[p & (BKT - 1)].x, v.x);
    atomicAdd(&av[p & (BKT - 1)].y, v.y);
  }
  __syncthreads();
  float2* dstp = pB + ((size_t)(k * S + s) << BKT_BITS);
  for (int t = threadIdx.x; t < BKT; t += AT) dstp[t] = av[t];
}

// ---- 6b. node epilogue B: sum partials + fused log-softmax ----
__global__ void __launch_bounds__(256) k_nodeB(
    const float2* __restrict__ pB, const float* __restrict__ dinv,
    const float2* __restrict__ yd, const float* __restrict__ b2, int S, int n,
    float2* __restrict__ out) {
  int g = blockIdx.x * 256 + threadIdx.x;
  if (g >= n) return;
  int k = g >> BKT_BITS, t = g & (BKT - 1);
  float s0 = 0.0f, s1 = 0.0f;
  for (int s = 0; s < S; ++s) {
    float2 v = pB[((size_t)(k * S + s) << BKT_BITS) + t];
    s0 += v.x;
    s1 += v.y;
  }
  float di = dinv[g];
  float2 yv = yd[g];
  float t0 = fmaf(di, s0 + yv.x, b2[0]);
  float t1 = fmaf(di, s1 + yv.y, b2[1]);
  float m = fmaxf(t0, t1);
  float l = m + logf(expf(t0 - m) + expf(t1 - m));
  out[g] = make_float2(t0 - l, t1 - l);
}

extern "C" void kernel_launch(void* const* d_in, const int* in_sizes, int n_in,
                              void* d_out, int out_size, void* d_ws, size_t ws_size,
                              hipStream_t stream) {
  const float* x = (const float*)d_in[0];
  const int* edge = (const int*)d_in[1];  // int64 inputs arrive as int32
  const float* W1 = (const float*)d_in[2];
  const float* b1 = (const float*)d_in[3];
  const float* W2 = (const float*)d_in[4];
  const float* b2 = (const float*)d_in[5];
  float2* out = (float2*)d_out;

  const int n = in_sizes[0];      // 500000
  const int e = in_sizes[1] / 2;  // 8000000
  const int* src = edge;
  const int* dst = edge + e;

  const int nbkt = (n + BKT - 1) >> BKT_BITS;         // 245
  const int hchunk = (((e + HB - 1) / HB) + 3) & ~3;  // mult of 4
  const int sgrid = (e + CHUNK - 1) / CHUNK;          // 977
  const int ngrid = (n + 255) / 256;                  // 1954

  // ---- workspace ----
  char* ws = (char*)d_ws;
  size_t off = 0;
  unsigned* packed = (unsigned*)(ws + off); off += (size_t)e * 4;
  unsigned* totals = (unsigned*)(ws + off); off += NB * 4;
  unsigned* gcur = (unsigned*)(ws + off);   off += NB * 4;
  float* dinv = (float*)(ws + off);         off += (size_t)n * 4;
  float* xs = (float*)(ws + off);           off += (size_t)n * 4;
  float2* yd = (float2*)(ws + off);         off += (size_t)n * 8;
  size_t rem = (ws_size > off) ? ws_size - off : 0;
  // pA (f32) and pB (float2) overlay the same region (pA dead before accB).
  int SA = (int)(rem / ((size_t)nbkt * BKT * 4));
  int SB = (int)(rem / ((size_t)nbkt * BKT * 8));
  SA = SA < 1 ? 1 : (SA > 8 ? 8 : SA);
  SB = SB < 1 ? 1 : (SB > 8 ? 8 : SB);
  float* pA = (float*)(ws + off);
  float2* pB = (float2*)(ws + off);

  hipMemsetAsync(totals, 0, NB * sizeof(unsigned), stream);
  k_hist<<<HB, HT, 0, stream>>>(dst, e, hchunk, nbkt, totals);
  k_basescan<<<1, 64, 0, stream>>>(totals, nbkt, gcur);
  k_scatter<<<sgrid, SCT, 0, stream>>>(src, dst, e, nbkt, gcur, packed);
  // after k_scatter: gcur[k] == end of bucket k
  k_degnode<<<nbkt, 1024, 0, stream>>>(packed, gcur, x, n, dinv, xs);
  k_accA_part<<<nbkt * SA, AT, 0, stream>>>(packed, gcur, xs, SA, pA);
  k_nodeA<<<ngrid, 256, 0, stream>>>(pA, dinv, xs, W1, b1, W2, SA, n, yd);
  k_accB_part<<<nbkt * SB, AT, 0, stream>>>(packed, gcur, yd, SB, pB);
  k_nodeB<<<ngrid, 256, 0, stream>>>(pB, dinv, yd, b2, SB, n, out);
}